// Round 1
// baseline (5729.835 us; speedup 1.0000x reference)
//
#include <hip/hip_runtime.h>
#include <hip/hip_bf16.h>

#define N_ 256
#define T_ 128
#define D_ 1024
#define H_ 1024
#define FH_ 4096
#define K2_ 2048

typedef __bf16 bf16x8 __attribute__((ext_vector_type(8)));
typedef float f32x4 __attribute__((ext_vector_type(4)));

// ---------------- transpose + cast fp32 -> bf16 ----------------
// dst[c][dst_coloff + r] = (bf16) src[r][c]
__global__ __launch_bounds__(256) void transpose_cast(
    const float* __restrict__ src, int cols,
    __hip_bfloat16* __restrict__ dst, int dst_stride, int dst_coloff)
{
    __shared__ float tile[32][33];
    int cb = blockIdx.x * 32, rb = blockIdx.y * 32;
    int tx = threadIdx.x, ty = threadIdx.y;  // (32, 8)
#pragma unroll
    for (int i = 0; i < 4; i++)
        tile[ty + i * 8][tx] = src[(size_t)(rb + ty + i * 8) * cols + cb + tx];
    __syncthreads();
#pragma unroll
    for (int i = 0; i < 4; i++)
        dst[(size_t)(cb + ty + i * 8) * dst_stride + dst_coloff + rb + tx] =
            __float2bfloat16(tile[tx][ty + i * 8]);
}

// ---------------- GEMM: C[m][j] = sum_k A[m][k] * BT[j][k] ----------------
// MODE 0: A = bf16 row-major [M][K] (the [h|attn] operand)
// MODE 1: A = fp32 x with row g -> (n = g&255, t = t0 + (g>>8)), cast on load
#define BM 64
#define BN 128
#define BK 64
#define BKP 72

template <int MODE>
__global__ __launch_bounds__(256) void gemm_bt(
    const float* __restrict__ Xf,
    const __hip_bfloat16* __restrict__ Ab,
    const __hip_bfloat16* __restrict__ BT,
    float* __restrict__ C, int K, int t0)
{
    __shared__ __hip_bfloat16 Al[BM][BKP];
    __shared__ __hip_bfloat16 Bl[BN][BKP];
    const int tid = threadIdx.x;
    const int lane = tid & 63, wid = tid >> 6;
    const int m0 = blockIdx.y * BM, n0 = blockIdx.x * BN;
    const int wm = (wid >> 1) * 32, wn = (wid & 1) * 64;
    const int rs = tid >> 3, kc = (tid & 7) * 8;
    f32x4 acc[2][4] = {};

    for (int k0 = 0; k0 < K; k0 += BK) {
        // stage A (64 rows x 64 k)
#pragma unroll
        for (int p = 0; p < BM; p += 32) {
            int r = rs + p;
            if constexpr (MODE == 0) {
                const __hip_bfloat16* s = Ab + (size_t)(m0 + r) * K + k0 + kc;
                *reinterpret_cast<int4*>(&Al[r][kc]) = *reinterpret_cast<const int4*>(s);
            } else {
                int g = m0 + r;
                int nn = g & 255, tl = g >> 8;
                const float* s = Xf + ((size_t)nn * T_ + (t0 + tl)) * D_ + k0 + kc;
                float4 v0 = *reinterpret_cast<const float4*>(s);
                float4 v1 = *reinterpret_cast<const float4*>(s + 4);
                __hip_bfloat16 h8[8];
                h8[0] = __float2bfloat16(v0.x); h8[1] = __float2bfloat16(v0.y);
                h8[2] = __float2bfloat16(v0.z); h8[3] = __float2bfloat16(v0.w);
                h8[4] = __float2bfloat16(v1.x); h8[5] = __float2bfloat16(v1.y);
                h8[6] = __float2bfloat16(v1.z); h8[7] = __float2bfloat16(v1.w);
                *reinterpret_cast<int4*>(&Al[r][kc]) = *reinterpret_cast<const int4*>(h8);
            }
        }
        // stage B (128 rows x 64 k)
#pragma unroll
        for (int p = 0; p < BN; p += 32) {
            int r = rs + p;
            const __hip_bfloat16* s = BT + (size_t)(n0 + r) * K + k0 + kc;
            *reinterpret_cast<int4*>(&Bl[r][kc]) = *reinterpret_cast<const int4*>(s);
        }
        __syncthreads();
        const int ko = (lane >> 4) * 8;
#pragma unroll
        for (int kk = 0; kk < BK; kk += 32) {
            bf16x8 a0 = *reinterpret_cast<const bf16x8*>(&Al[wm + (lane & 15)][kk + ko]);
            bf16x8 a1 = *reinterpret_cast<const bf16x8*>(&Al[wm + 16 + (lane & 15)][kk + ko]);
#pragma unroll
            for (int ni = 0; ni < 4; ni++) {
                bf16x8 bq = *reinterpret_cast<const bf16x8*>(&Bl[wn + ni * 16 + (lane & 15)][kk + ko]);
                acc[0][ni] = __builtin_amdgcn_mfma_f32_16x16x32_bf16(a0, bq, acc[0][ni], 0, 0, 0);
                acc[1][ni] = __builtin_amdgcn_mfma_f32_16x16x32_bf16(a1, bq, acc[1][ni], 0, 0, 0);
            }
        }
        __syncthreads();
    }
    const int cr = (lane >> 4) * 4, ccol = lane & 15;
#pragma unroll
    for (int mi = 0; mi < 2; mi++)
#pragma unroll
        for (int ni = 0; ni < 4; ni++)
#pragma unroll
            for (int r = 0; r < 4; r++)
                C[(size_t)(m0 + wm + mi * 16 + cr + r) * FH_ + (n0 + wn + ni * 16 + ccol)] =
                    acc[mi][ni][r];
}

// ---------------- attention tail (shared by init and gates kernels) ----------
// block = 1024 threads (one n per block); a[16] = A_flat[n][hh][:] in regs.
__device__ __forceinline__ void attention_tail(
    const float* a, float h, int n, int hh,
    __hip_bfloat16* __restrict__ hb, float* sred, float* wsm)
{
    const int tid = threadIdx.x;
    const int lane = tid & 63, wv = tid >> 6;
    float p[16];
#pragma unroll
    for (int l = 0; l < 16; l++) p[l] = h * a[l];
#pragma unroll
    for (int l = 0; l < 16; l++) {
        float v = p[l];
        v += __shfl_down(v, 32); v += __shfl_down(v, 16); v += __shfl_down(v, 8);
        v += __shfl_down(v, 4);  v += __shfl_down(v, 2);  v += __shfl_down(v, 1);
        if (lane == 0) sred[wv * 16 + l] = v;
    }
    __syncthreads();
    if (tid < 16) {
        float s = 0.f;
#pragma unroll
        for (int w = 0; w < 16; w++) s += sred[w * 16 + tid];
        s *= 0.03125f;  // 1/sqrt(1024)
        float m = s;
        m = fmaxf(m, __shfl_xor(m, 8)); m = fmaxf(m, __shfl_xor(m, 4));
        m = fmaxf(m, __shfl_xor(m, 2)); m = fmaxf(m, __shfl_xor(m, 1));
        float e = expf(s - m);
        float se = e;
        se += __shfl_xor(se, 8); se += __shfl_xor(se, 4);
        se += __shfl_xor(se, 2); se += __shfl_xor(se, 1);
        wsm[tid] = e / se;
    }
    __syncthreads();
    float attn = 0.f;
#pragma unroll
    for (int l = 0; l < 16; l++) attn += a[l] * wsm[l];
    hb[(size_t)n * K2_ + H_ + hh] = __float2bfloat16(attn);
}

// ---------------- init: h0 = c0 = mean(A), then attention ----------------
__global__ __launch_bounds__(1024) void init_hc(
    const float* __restrict__ A, float* __restrict__ c, __hip_bfloat16* __restrict__ hb)
{
    __shared__ float sred[256];
    __shared__ float wsm[16];
    const int n = blockIdx.x, hh = threadIdx.x;
    const float4* Ap = reinterpret_cast<const float4*>(A + ((size_t)n * H_ + hh) * 16);
    float4 q0 = Ap[0], q1 = Ap[1], q2 = Ap[2], q3 = Ap[3];
    float a[16] = {q0.x, q0.y, q0.z, q0.w, q1.x, q1.y, q1.z, q1.w,
                   q2.x, q2.y, q2.z, q2.w, q3.x, q3.y, q3.z, q3.w};
    float s = 0.f;
#pragma unroll
    for (int l = 0; l < 16; l++) s += a[l];
    float h0 = s * 0.0625f;
    c[(size_t)n * H_ + hh] = h0;
    hb[(size_t)n * K2_ + hh] = __float2bfloat16(h0);
    attention_tail(a, h0, n, hh, hb, sred, wsm);
}

// ---------------- gates + output + attention ----------------
__global__ __launch_bounds__(1024) void gates_attn(
    const float* __restrict__ pre, const float* __restrict__ xp,
    const float* __restrict__ b, const float* __restrict__ A,
    float* __restrict__ c, __hip_bfloat16* __restrict__ hb,
    float* __restrict__ out, int t)
{
    __shared__ float sred[256];
    __shared__ float wsm[16];
    const int n = blockIdx.x, hh = threadIdx.x;
    const size_t base = (size_t)n * FH_;
    float pi = pre[base + hh]        + xp[base + hh]        + b[hh];
    float pf = pre[base + 1024 + hh] + xp[base + 1024 + hh] + b[1024 + hh];
    float po = pre[base + 2048 + hh] + xp[base + 2048 + hh] + b[2048 + hh];
    float pg = pre[base + 3072 + hh] + xp[base + 3072 + hh] + b[3072 + hh];
    float iv = 1.f / (1.f + expf(-pi));
    float fv = 1.f / (1.f + expf(-pf));
    float ov = 1.f / (1.f + expf(-po));
    float gv = tanhf(pg);
    const size_t ch = (size_t)n * H_ + hh;
    float cc = fv * c[ch] + iv * gv;
    c[ch] = cc;
    float h = ov * tanhf(cc);
    out[((size_t)n * T_ + t) * H_ + hh] = h;
    hb[(size_t)n * K2_ + hh] = __float2bfloat16(h);
    const float4* Ap = reinterpret_cast<const float4*>(A + ((size_t)n * H_ + hh) * 16);
    float4 q0 = Ap[0], q1 = Ap[1], q2 = Ap[2], q3 = Ap[3];
    float a[16] = {q0.x, q0.y, q0.z, q0.w, q1.x, q1.y, q1.z, q1.w,
                   q2.x, q2.y, q2.z, q2.w, q3.x, q3.y, q3.z, q3.w};
    attention_tail(a, h, n, hh, hb, sred, wsm);
}

extern "C" void kernel_launch(void* const* d_in, const int* in_sizes, int n_in,
                              void* d_out, int out_size, void* d_ws, size_t ws_size,
                              hipStream_t stream)
{
    const float* x     = (const float*)d_in[0];
    const float* A     = (const float*)d_in[1];
    const float* Wx    = (const float*)d_in[2];
    const float* Wh    = (const float*)d_in[3];
    const float* Wattn = (const float*)d_in[4];
    const float* b     = (const float*)d_in[5];
    float* out = (float*)d_out;

    char* ws = (char*)d_ws;
    size_t off = 0;
    __hip_bfloat16* W2T = (__hip_bfloat16*)(ws + off); off += (size_t)FH_ * K2_ * 2;  // 16.8 MB
    __hip_bfloat16* WxT = (__hip_bfloat16*)(ws + off); off += (size_t)FH_ * D_ * 2;   // 8.4 MB
    float* pre  = (float*)(ws + off); off += (size_t)N_ * FH_ * 4;                    // 4.2 MB
    __hip_bfloat16* hb = (__hip_bfloat16*)(ws + off); off += (size_t)N_ * K2_ * 2;    // 1 MB
    float* cbuf = (float*)(ws + off); off += (size_t)N_ * H_ * 4;                     // 1 MB
    float* xproj = (float*)(ws + off);
    size_t per_t = (size_t)N_ * FH_ * 4;  // 4.2 MB per timestep
    size_t rem = (ws_size > off) ? (ws_size - off) : 0;
    int Tc = (int)(rem / per_t);
    if (Tc > 16) Tc = 16;
    if (Tc < 1) Tc = 1;  // hope ws is at least ~36 MB

    // one-time (per launch) weight prep
    dim3 tb(32, 8);
    transpose_cast<<<dim3(FH_ / 32, H_ / 32), tb, 0, stream>>>(Wh, FH_, W2T, K2_, 0);
    transpose_cast<<<dim3(FH_ / 32, H_ / 32), tb, 0, stream>>>(Wattn, FH_, W2T, K2_, H_);
    transpose_cast<<<dim3(FH_ / 32, D_ / 32), tb, 0, stream>>>(Wx, FH_, WxT, D_, 0);
    init_hc<<<N_, 1024, 0, stream>>>(A, cbuf, hb);

    for (int t0 = 0; t0 < T_; t0 += Tc) {
        int tc = (T_ - t0 < Tc) ? (T_ - t0) : Tc;
        // xproj[tl][n][:] = x[n][t0+tl][:] @ Wx
        dim3 gx(FH_ / BN, tc * N_ / BM);
        gemm_bt<1><<<gx, 256, 0, stream>>>(x, nullptr, WxT, xproj, D_, t0);
        for (int tl = 0; tl < tc; tl++) {
            int t = t0 + tl;
            dim3 gs(FH_ / BN, N_ / BM);
            gemm_bt<0><<<gs, 256, 0, stream>>>(nullptr, hb, W2T, pre, K2_, 0);
            gates_attn<<<N_, 1024, 0, stream>>>(pre, xproj + (size_t)tl * N_ * FH_,
                                                b, A, cbuf, hb, out, t);
        }
    }
}

// Round 2
// 3951.963 us; speedup vs baseline: 1.4499x; 1.4499x over previous
//
#include <hip/hip_runtime.h>
#include <hip/hip_bf16.h>
#include <stdint.h>

#define N_ 256
#define T_ 128
#define D_ 1024
#define H_ 1024
#define FH_ 4096
#define K2_ 2048

typedef __bf16 bf16x8 __attribute__((ext_vector_type(8)));
typedef float f32x4 __attribute__((ext_vector_type(4)));

// ---------------- transpose + cast fp32 -> bf16 ----------------
// dst[c][dst_coloff + r] = (bf16) src[r][c]
__global__ __launch_bounds__(256) void transpose_cast(
    const float* __restrict__ src, int cols,
    __hip_bfloat16* __restrict__ dst, int dst_stride, int dst_coloff)
{
    __shared__ float tile[32][33];
    int cb = blockIdx.x * 32, rb = blockIdx.y * 32;
    int tx = threadIdx.x, ty = threadIdx.y;  // (32, 8)
#pragma unroll
    for (int i = 0; i < 4; i++)
        tile[ty + i * 8][tx] = src[(size_t)(rb + ty + i * 8) * cols + cb + tx];
    __syncthreads();
#pragma unroll
    for (int i = 0; i < 4; i++)
        dst[(size_t)(cb + ty + i * 8) * dst_stride + dst_coloff + rb + tx] =
            __float2bfloat16(tile[tx][ty + i * 8]);
}

// ---------------- GEMM: C[m][j] = sum_k A[m][k] * BT[j][k] ----------------
#define BM 64
#define BN 128
#define BK 64
#define BKP 72

template <int MODE>
__global__ __launch_bounds__(256) void gemm_bt(
    const float* __restrict__ Xf,
    const __hip_bfloat16* __restrict__ Ab,
    const __hip_bfloat16* __restrict__ BT,
    float* __restrict__ C, int K, int t0)
{
    __shared__ __hip_bfloat16 Al[BM][BKP];
    __shared__ __hip_bfloat16 Bl[BN][BKP];
    const int tid = threadIdx.x;
    const int lane = tid & 63, wid = tid >> 6;
    const int m0 = blockIdx.y * BM, n0 = blockIdx.x * BN;
    const int wm = (wid >> 1) * 32, wn = (wid & 1) * 64;
    const int rs = tid >> 3, kc = (tid & 7) * 8;
    f32x4 acc[2][4] = {};

    for (int k0 = 0; k0 < K; k0 += BK) {
#pragma unroll
        for (int p = 0; p < BM; p += 32) {
            int r = rs + p;
            if constexpr (MODE == 0) {
                const __hip_bfloat16* s = Ab + (size_t)(m0 + r) * K + k0 + kc;
                *reinterpret_cast<int4*>(&Al[r][kc]) = *reinterpret_cast<const int4*>(s);
            } else {
                int g = m0 + r;
                int nn = g & 255, tl = g >> 8;
                const float* s = Xf + ((size_t)nn * T_ + (t0 + tl)) * D_ + k0 + kc;
                float4 v0 = *reinterpret_cast<const float4*>(s);
                float4 v1 = *reinterpret_cast<const float4*>(s + 4);
                __hip_bfloat16 h8[8];
                h8[0] = __float2bfloat16(v0.x); h8[1] = __float2bfloat16(v0.y);
                h8[2] = __float2bfloat16(v0.z); h8[3] = __float2bfloat16(v0.w);
                h8[4] = __float2bfloat16(v1.x); h8[5] = __float2bfloat16(v1.y);
                h8[6] = __float2bfloat16(v1.z); h8[7] = __float2bfloat16(v1.w);
                *reinterpret_cast<int4*>(&Al[r][kc]) = *reinterpret_cast<const int4*>(h8);
            }
        }
#pragma unroll
        for (int p = 0; p < BN; p += 32) {
            int r = rs + p;
            const __hip_bfloat16* s = BT + (size_t)(n0 + r) * K + k0 + kc;
            *reinterpret_cast<int4*>(&Bl[r][kc]) = *reinterpret_cast<const int4*>(s);
        }
        __syncthreads();
        const int ko = (lane >> 4) * 8;
#pragma unroll
        for (int kk = 0; kk < BK; kk += 32) {
            bf16x8 a0 = *reinterpret_cast<const bf16x8*>(&Al[wm + (lane & 15)][kk + ko]);
            bf16x8 a1 = *reinterpret_cast<const bf16x8*>(&Al[wm + 16 + (lane & 15)][kk + ko]);
#pragma unroll
            for (int ni = 0; ni < 4; ni++) {
                bf16x8 bq = *reinterpret_cast<const bf16x8*>(&Bl[wn + ni * 16 + (lane & 15)][kk + ko]);
                acc[0][ni] = __builtin_amdgcn_mfma_f32_16x16x32_bf16(a0, bq, acc[0][ni], 0, 0, 0);
                acc[1][ni] = __builtin_amdgcn_mfma_f32_16x16x32_bf16(a1, bq, acc[1][ni], 0, 0, 0);
            }
        }
        __syncthreads();
    }
    const int cr = (lane >> 4) * 4, ccol = lane & 15;
#pragma unroll
    for (int mi = 0; mi < 2; mi++)
#pragma unroll
        for (int ni = 0; ni < 4; ni++)
#pragma unroll
            for (int r = 0; r < 4; r++)
                C[(size_t)(m0 + wm + mi * 16 + cr + r) * FH_ + (n0 + wn + ni * 16 + ccol)] =
                    acc[mi][ni][r];
}

// ---------------- AW precompute: AW[n][j][l] = sum_h A[n,h,l]*Wattn[h,j] ---
__global__ __launch_bounds__(256) void aw_gemm(
    const float* __restrict__ A, const __hip_bfloat16* __restrict__ WaT,
    __hip_bfloat16* __restrict__ AW)
{
    __shared__ __hip_bfloat16 Al[16][72];
    __shared__ __hip_bfloat16 Bl[128][72];
    const int tid = threadIdx.x, lane = tid & 63, wv = tid >> 6;
    const int n = blockIdx.y, j0 = blockIdx.x * 128;
    const int rs = tid >> 3, kc = (tid & 7) * 8;
    f32x4 acc[2] = {};
    for (int k0 = 0; k0 < 1024; k0 += 64) {
        {
            int h = tid >> 2, lq = (tid & 3) * 4;
            float4 v = *reinterpret_cast<const float4*>(A + ((size_t)n * 1024 + k0 + h) * 16 + lq);
            Al[lq + 0][h] = __float2bfloat16(v.x);
            Al[lq + 1][h] = __float2bfloat16(v.y);
            Al[lq + 2][h] = __float2bfloat16(v.z);
            Al[lq + 3][h] = __float2bfloat16(v.w);
        }
#pragma unroll
        for (int p = 0; p < 128; p += 32) {
            int r = rs + p;
            *reinterpret_cast<int4*>(&Bl[r][kc]) =
                *reinterpret_cast<const int4*>(WaT + (size_t)(j0 + r) * 1024 + k0 + kc);
        }
        __syncthreads();
        const int ko = (lane >> 4) * 8;
#pragma unroll
        for (int kk = 0; kk < 64; kk += 32) {
            bf16x8 a0 = *reinterpret_cast<const bf16x8*>(&Al[lane & 15][kk + ko]);
#pragma unroll
            for (int nf = 0; nf < 2; nf++) {
                bf16x8 bq = *reinterpret_cast<const bf16x8*>(&Bl[wv * 32 + nf * 16 + (lane & 15)][kk + ko]);
                acc[nf] = __builtin_amdgcn_mfma_f32_16x16x32_bf16(a0, bq, acc[nf], 0, 0, 0);
            }
        }
        __syncthreads();
    }
    const int cr = (lane >> 4) * 4, cc = lane & 15;
#pragma unroll
    for (int nf = 0; nf < 2; nf++) {
        __hip_bfloat16 t4[4];
#pragma unroll
        for (int r = 0; r < 4; r++) t4[r] = __float2bfloat16(acc[nf][r]);
        *reinterpret_cast<uint2*>(AW + ((size_t)n * 4096 + j0 + wv * 32 + nf * 16 + cc) * 16 + cr) =
            *reinterpret_cast<uint2*>(t4);
    }
}

// ---------------- init (new path): h0, c0, score partials ----------------
__global__ __launch_bounds__(1024) void init2(
    const float* __restrict__ A, float* __restrict__ c,
    __hip_bfloat16* __restrict__ hb, float* __restrict__ sp)
{
    __shared__ float sred[16][16];
    const int n = blockIdx.x, hh = threadIdx.x;
    const int lane = hh & 63, wv = hh >> 6;
    const float4* Ap = reinterpret_cast<const float4*>(A + ((size_t)n * 1024 + hh) * 16);
    float4 q0 = Ap[0], q1 = Ap[1], q2 = Ap[2], q3 = Ap[3];
    float a[16] = {q0.x, q0.y, q0.z, q0.w, q1.x, q1.y, q1.z, q1.w,
                   q2.x, q2.y, q2.z, q2.w, q3.x, q3.y, q3.z, q3.w};
    float s = 0.f;
#pragma unroll
    for (int l = 0; l < 16; l++) s += a[l];
    float h0 = s * 0.0625f;
    c[(size_t)n * 1024 + hh] = h0;
    hb[(size_t)n * 1024 + hh] = __float2bfloat16(h0);
#pragma unroll
    for (int l = 0; l < 16; l++) {
        float v = h0 * a[l];
        v += __shfl_down(v, 32); v += __shfl_down(v, 16); v += __shfl_down(v, 8);
        v += __shfl_down(v, 4);  v += __shfl_down(v, 2);  v += __shfl_down(v, 1);
        if (lane == 0) sred[wv][l] = v;
    }
    __syncthreads();
    if (hh < 512) {
        float val = 0.f;
        if (hh < 16) {
#pragma unroll
            for (int w = 0; w < 16; w++) val += sred[w][hh];
        }
        sp[(size_t)n * 512 + hh] = val;  // jt=0 gets raw scores, jt>=1 zero
    }
}

// ---------------- fused per-step kernel ----------------
// grid (32 jt, 8 mt), block 256. Each WG: 32 n-rows x 32 hidden cols,
// all 4 gate sections. One launch per timestep.
__global__ __launch_bounds__(256) void fused_step(
    const __hip_bfloat16* __restrict__ hb_in,
    __hip_bfloat16* __restrict__ hb_out,
    const float* __restrict__ sp_in,
    float* __restrict__ sp_out,
    const __hip_bfloat16* __restrict__ WhT,
    const __hip_bfloat16* __restrict__ AW,
    const float* __restrict__ xp,
    const float* __restrict__ bias,
    const float* __restrict__ Afp,
    float* __restrict__ cbuf,
    float* __restrict__ out, int t)
{
    __shared__ __hip_bfloat16 Al[32][72];
    __shared__ __hip_bfloat16 Bl[128][72];
    __shared__ float pls[4][32][33];
    __shared__ float wsm[32][16];

    const int tid = threadIdx.x;
    const int lane = tid & 63, wv = tid >> 6;
    const int jt = blockIdx.x, mt = blockIdx.y;
    const int n0 = mt * 32, col0 = jt * 32;

    // ---- softmax weights from previous step's score partials ----
    {
        const int n = tid >> 3, li = tid & 7;
        const float* sp = sp_in + (size_t)(n0 + n) * 512;
        float s0 = 0.f, s1 = 0.f;
#pragma unroll
        for (int j = 0; j < 32; j++) { s0 += sp[j * 16 + li]; s1 += sp[j * 16 + li + 8]; }
        s0 *= 0.03125f; s1 *= 0.03125f;
        float m = fmaxf(s0, s1);
        m = fmaxf(m, __shfl_xor(m, 1));
        m = fmaxf(m, __shfl_xor(m, 2));
        m = fmaxf(m, __shfl_xor(m, 4));
        float e0 = __expf(s0 - m), e1 = __expf(s1 - m);
        float se = e0 + e1;
        se += __shfl_xor(se, 1); se += __shfl_xor(se, 2); se += __shfl_xor(se, 4);
        float inv = 1.f / se;
        wsm[n][li] = e0 * inv;
        wsm[n][li + 8] = e1 * inv;
    }

    // ---- GEMM: pre_raw[s][n][j] = h_prev @ Wh[:, s*1024+col0+j] ----
    f32x4 acc[2][2] = {};
    const int rs = tid >> 3, kc = (tid & 7) * 8;
    for (int k0 = 0; k0 < 1024; k0 += 64) {
        *reinterpret_cast<int4*>(&Al[rs][kc]) =
            *reinterpret_cast<const int4*>(hb_in + (size_t)(n0 + rs) * 1024 + k0 + kc);
#pragma unroll
        for (int p = 0; p < 128; p += 32) {
            int r = rs + p;
            int grow = (r >> 5) * 1024 + col0 + (r & 31);
            *reinterpret_cast<int4*>(&Bl[r][kc]) =
                *reinterpret_cast<const int4*>(WhT + (size_t)grow * 1024 + k0 + kc);
        }
        __syncthreads();
        const int ko = (lane >> 4) * 8;
#pragma unroll
        for (int kk = 0; kk < 64; kk += 32) {
            bf16x8 a0 = *reinterpret_cast<const bf16x8*>(&Al[lane & 15][kk + ko]);
            bf16x8 a1 = *reinterpret_cast<const bf16x8*>(&Al[16 + (lane & 15)][kk + ko]);
#pragma unroll
            for (int nf = 0; nf < 2; nf++) {
                bf16x8 bq = *reinterpret_cast<const bf16x8*>(&Bl[wv * 32 + nf * 16 + (lane & 15)][kk + ko]);
                acc[0][nf] = __builtin_amdgcn_mfma_f32_16x16x32_bf16(a0, bq, acc[0][nf], 0, 0, 0);
                acc[1][nf] = __builtin_amdgcn_mfma_f32_16x16x32_bf16(a1, bq, acc[1][nf], 0, 0, 0);
            }
        }
        __syncthreads();
    }
    {
        const int cr = (lane >> 4) * 4, cc = lane & 15;
#pragma unroll
        for (int mf = 0; mf < 2; mf++)
#pragma unroll
            for (int nf = 0; nf < 2; nf++)
#pragma unroll
                for (int r = 0; r < 4; r++)
                    pls[wv][mf * 16 + cr + r][nf * 16 + cc] = acc[mf][nf][r];
    }
    __syncthreads();

    // ---- gates + c/h update + output + next score partials ----
    {
        const int n = tid >> 3;
        const int q0 = (tid & 7) * 4;
        const int gn = n0 + n;
        float w[16];
        *reinterpret_cast<float4*>(&w[0])  = *reinterpret_cast<const float4*>(&wsm[n][0]);
        *reinterpret_cast<float4*>(&w[4])  = *reinterpret_cast<const float4*>(&wsm[n][4]);
        *reinterpret_cast<float4*>(&w[8])  = *reinterpret_cast<const float4*>(&wsm[n][8]);
        *reinterpret_cast<float4*>(&w[12]) = *reinterpret_cast<const float4*>(&wsm[n][12]);
        float pre_[4][4];
#pragma unroll
        for (int s = 0; s < 4; s++) {
            const int gj = s * 1024 + col0 + q0;
            float xv[4], bv[4];
            *reinterpret_cast<float4*>(xv) = *reinterpret_cast<const float4*>(xp + (size_t)gn * 4096 + gj);
            *reinterpret_cast<float4*>(bv) = *reinterpret_cast<const float4*>(bias + gj);
            const __hip_bfloat16* aw = AW + ((size_t)gn * 4096 + gj) * 16;
#pragma unroll
            for (int q = 0; q < 4; q++) {
                bf16x8 a0 = *reinterpret_cast<const bf16x8*>(aw + q * 16);
                bf16x8 a1 = *reinterpret_cast<const bf16x8*>(aw + q * 16 + 8);
                float sa = 0.f;
#pragma unroll
                for (int l = 0; l < 8; l++) sa += w[l] * (float)a0[l];
#pragma unroll
                for (int l = 0; l < 8; l++) sa += w[l + 8] * (float)a1[l];
                pre_[s][q] = pls[s][n][q0 + q] + xv[q] + bv[q] + sa;
            }
        }
        float cv[4];
        *reinterpret_cast<float4*>(cv) = *reinterpret_cast<const float4*>(cbuf + (size_t)gn * 1024 + col0 + q0);
        float hq[4];
#pragma unroll
        for (int q = 0; q < 4; q++) {
            float iv = 1.f / (1.f + __expf(-pre_[0][q]));
            float fv = 1.f / (1.f + __expf(-pre_[1][q]));
            float ov = 1.f / (1.f + __expf(-pre_[2][q]));
            float gx = fminf(fmaxf(pre_[3][q], -20.f), 20.f);
            float eg = __expf(2.f * gx);
            float gv = (eg - 1.f) / (eg + 1.f);
            float cc2 = fv * cv[q] + iv * gv;
            cv[q] = cc2;
            float cx = fminf(fmaxf(cc2, -20.f), 20.f);
            float ec = __expf(2.f * cx);
            hq[q] = ov * (ec - 1.f) / (ec + 1.f);
        }
        *reinterpret_cast<float4*>(cbuf + (size_t)gn * 1024 + col0 + q0) = *reinterpret_cast<float4*>(cv);
        *reinterpret_cast<float4*>(out + ((size_t)gn * T_ + t) * 1024 + col0 + q0) = *reinterpret_cast<float4*>(hq);
        __hip_bfloat16 h4[4];
#pragma unroll
        for (int q = 0; q < 4; q++) h4[q] = __float2bfloat16(hq[q]);
        *reinterpret_cast<uint2*>(hb_out + (size_t)gn * 1024 + col0 + q0) = *reinterpret_cast<uint2*>(h4);

        float spv[16];
#pragma unroll
        for (int l = 0; l < 16; l++) spv[l] = 0.f;
#pragma unroll
        for (int q = 0; q < 4; q++) {
            const float* ar = Afp + ((size_t)gn * 1024 + col0 + q0 + q) * 16;
            float av[16];
            *reinterpret_cast<float4*>(&av[0])  = *reinterpret_cast<const float4*>(ar);
            *reinterpret_cast<float4*>(&av[4])  = *reinterpret_cast<const float4*>(ar + 4);
            *reinterpret_cast<float4*>(&av[8])  = *reinterpret_cast<const float4*>(ar + 8);
            *reinterpret_cast<float4*>(&av[12]) = *reinterpret_cast<const float4*>(ar + 12);
#pragma unroll
            for (int l = 0; l < 16; l++) spv[l] += hq[q] * av[l];
        }
#pragma unroll
        for (int l = 0; l < 16; l++) {
            spv[l] += __shfl_xor(spv[l], 1);
            spv[l] += __shfl_xor(spv[l], 2);
            spv[l] += __shfl_xor(spv[l], 4);
        }
        if ((tid & 7) == 0) {
            float* d = sp_out + ((size_t)gn * 32 + jt) * 16;
            *reinterpret_cast<float4*>(d)      = *reinterpret_cast<float4*>(&spv[0]);
            *reinterpret_cast<float4*>(d + 4)  = *reinterpret_cast<float4*>(&spv[4]);
            *reinterpret_cast<float4*>(d + 8)  = *reinterpret_cast<float4*>(&spv[8]);
            *reinterpret_cast<float4*>(d + 12) = *reinterpret_cast<float4*>(&spv[12]);
        }
    }
}

// ================= fallback (round-1) kernels =================
__device__ __forceinline__ void attention_tail(
    const float* a, float h, int n, int hh,
    __hip_bfloat16* __restrict__ hb, float* sred, float* wsm)
{
    const int tid = threadIdx.x;
    const int lane = tid & 63, wv = tid >> 6;
    float p[16];
#pragma unroll
    for (int l = 0; l < 16; l++) p[l] = h * a[l];
#pragma unroll
    for (int l = 0; l < 16; l++) {
        float v = p[l];
        v += __shfl_down(v, 32); v += __shfl_down(v, 16); v += __shfl_down(v, 8);
        v += __shfl_down(v, 4);  v += __shfl_down(v, 2);  v += __shfl_down(v, 1);
        if (lane == 0) sred[wv * 16 + l] = v;
    }
    __syncthreads();
    if (tid < 16) {
        float s = 0.f;
#pragma unroll
        for (int w = 0; w < 16; w++) s += sred[w * 16 + tid];
        s *= 0.03125f;
        float m = s;
        m = fmaxf(m, __shfl_xor(m, 8)); m = fmaxf(m, __shfl_xor(m, 4));
        m = fmaxf(m, __shfl_xor(m, 2)); m = fmaxf(m, __shfl_xor(m, 1));
        float e = expf(s - m);
        float se = e;
        se += __shfl_xor(se, 8); se += __shfl_xor(se, 4);
        se += __shfl_xor(se, 2); se += __shfl_xor(se, 1);
        wsm[tid] = e / se;
    }
    __syncthreads();
    float attn = 0.f;
#pragma unroll
    for (int l = 0; l < 16; l++) attn += a[l] * wsm[l];
    hb[(size_t)n * K2_ + H_ + hh] = __float2bfloat16(attn);
}

__global__ __launch_bounds__(1024) void init_hc(
    const float* __restrict__ A, float* __restrict__ c, __hip_bfloat16* __restrict__ hb)
{
    __shared__ float sred[256];
    __shared__ float wsm[16];
    const int n = blockIdx.x, hh = threadIdx.x;
    const float4* Ap = reinterpret_cast<const float4*>(A + ((size_t)n * H_ + hh) * 16);
    float4 q0 = Ap[0], q1 = Ap[1], q2 = Ap[2], q3 = Ap[3];
    float a[16] = {q0.x, q0.y, q0.z, q0.w, q1.x, q1.y, q1.z, q1.w,
                   q2.x, q2.y, q2.z, q2.w, q3.x, q3.y, q3.z, q3.w};
    float s = 0.f;
#pragma unroll
    for (int l = 0; l < 16; l++) s += a[l];
    float h0 = s * 0.0625f;
    c[(size_t)n * H_ + hh] = h0;
    hb[(size_t)n * K2_ + hh] = __float2bfloat16(h0);
    attention_tail(a, h0, n, hh, hb, sred, wsm);
}

__global__ __launch_bounds__(1024) void gates_attn(
    const float* __restrict__ pre, const float* __restrict__ xp,
    const float* __restrict__ b, const float* __restrict__ A,
    float* __restrict__ c, __hip_bfloat16* __restrict__ hb,
    float* __restrict__ out, int t)
{
    __shared__ float sred[256];
    __shared__ float wsm[16];
    const int n = blockIdx.x, hh = threadIdx.x;
    const size_t base = (size_t)n * FH_;
    float pi = pre[base + hh]        + xp[base + hh]        + b[hh];
    float pf = pre[base + 1024 + hh] + xp[base + 1024 + hh] + b[1024 + hh];
    float po = pre[base + 2048 + hh] + xp[base + 2048 + hh] + b[2048 + hh];
    float pg = pre[base + 3072 + hh] + xp[base + 3072 + hh] + b[3072 + hh];
    float iv = 1.f / (1.f + expf(-pi));
    float fv = 1.f / (1.f + expf(-pf));
    float ov = 1.f / (1.f + expf(-po));
    float gv = tanhf(pg);
    const size_t ch = (size_t)n * H_ + hh;
    float cc = fv * c[ch] + iv * gv;
    c[ch] = cc;
    float h = ov * tanhf(cc);
    out[((size_t)n * T_ + t) * H_ + hh] = h;
    hb[(size_t)n * K2_ + hh] = __float2bfloat16(h);
    const float4* Ap = reinterpret_cast<const float4*>(A + ((size_t)n * H_ + hh) * 16);
    float4 q0 = Ap[0], q1 = Ap[1], q2 = Ap[2], q3 = Ap[3];
    float a[16] = {q0.x, q0.y, q0.z, q0.w, q1.x, q1.y, q1.z, q1.w,
                   q2.x, q2.y, q2.z, q2.w, q3.x, q3.y, q3.z, q3.w};
    attention_tail(a, h, n, hh, hb, sred, wsm);
}

extern "C" void kernel_launch(void* const* d_in, const int* in_sizes, int n_in,
                              void* d_out, int out_size, void* d_ws, size_t ws_size,
                              hipStream_t stream)
{
    const float* x     = (const float*)d_in[0];
    const float* A     = (const float*)d_in[1];
    const float* Wx    = (const float*)d_in[2];
    const float* Wh    = (const float*)d_in[3];
    const float* Wattn = (const float*)d_in[4];
    const float* b     = (const float*)d_in[5];
    float* out = (float*)d_out;
    char* ws = (char*)d_ws;
    dim3 tb(32, 8);

    // ---- new-path workspace layout ----
    const size_t SZ_WhT = (size_t)FH_ * H_ * 2;        // 8.4 MB
    const size_t SZ_WxT = (size_t)FH_ * D_ * 2;        // 8.4 MB
    const size_t SZ_AW  = (size_t)N_ * FH_ * 16 * 2;   // 33.5 MB
    const size_t SZ_HB  = (size_t)N_ * H_ * 2;         // 512 KB (x2)
    const size_t SZ_C   = (size_t)N_ * H_ * 4;         // 1 MB
    const size_t SZ_SP  = (size_t)N_ * 32 * 16 * 4;    // 512 KB (x2)
    const size_t SZ_XPT = (size_t)N_ * FH_ * 4;        // 4.2 MB per t
    const size_t fixed_new = SZ_WhT + SZ_WxT + SZ_AW + 2 * SZ_HB + SZ_C + 2 * SZ_SP;
    const size_t need_new = fixed_new + 2 * SZ_XPT;    // Tc>=2 so WaT alias fits

    if (ws_size >= need_new) {
        size_t off = 0;
        __hip_bfloat16* WhT = (__hip_bfloat16*)(ws + off); off += SZ_WhT;
        __hip_bfloat16* WxT = (__hip_bfloat16*)(ws + off); off += SZ_WxT;
        __hip_bfloat16* AW  = (__hip_bfloat16*)(ws + off); off += SZ_AW;
        __hip_bfloat16* hb0 = (__hip_bfloat16*)(ws + off); off += SZ_HB;
        __hip_bfloat16* hb1 = (__hip_bfloat16*)(ws + off); off += SZ_HB;
        float* cbuf = (float*)(ws + off); off += SZ_C;
        float* sp0  = (float*)(ws + off); off += SZ_SP;
        float* sp1  = (float*)(ws + off); off += SZ_SP;
        float* xproj = (float*)(ws + off);
        __hip_bfloat16* WaT = (__hip_bfloat16*)(ws + off);  // aliases xproj region
        int Tc = (int)((ws_size - off) / SZ_XPT);
        if (Tc > 16) Tc = 16;

        transpose_cast<<<dim3(FH_ / 32, H_ / 32), tb, 0, stream>>>(Wh, FH_, WhT, H_, 0);
        transpose_cast<<<dim3(FH_ / 32, D_ / 32), tb, 0, stream>>>(Wx, FH_, WxT, D_, 0);
        transpose_cast<<<dim3(FH_ / 32, H_ / 32), tb, 0, stream>>>(Wattn, FH_, WaT, H_, 0);
        aw_gemm<<<dim3(32, N_), 256, 0, stream>>>(A, WaT, AW);
        init2<<<N_, 1024, 0, stream>>>(A, cbuf, hb0, sp0);

        __hip_bfloat16* hbp[2] = {hb0, hb1};
        float* spp[2] = {sp0, sp1};
        for (int t0 = 0; t0 < T_; t0 += Tc) {
            int tc = (T_ - t0 < Tc) ? (T_ - t0) : Tc;
            dim3 gx(FH_ / BN, tc * N_ / BM);
            gemm_bt<1><<<gx, 256, 0, stream>>>(x, nullptr, WxT, xproj, D_, t0);
            for (int tl = 0; tl < tc; tl++) {
                int t = t0 + tl;
                fused_step<<<dim3(32, 8), 256, 0, stream>>>(
                    hbp[t & 1], hbp[(t + 1) & 1], spp[t & 1], spp[(t + 1) & 1],
                    WhT, AW, xproj + (size_t)tl * N_ * FH_, b, A, cbuf, out, t);
            }
        }
        return;
    }

    // ---- fallback: round-1 path ----
    size_t off = 0;
    __hip_bfloat16* W2T = (__hip_bfloat16*)(ws + off); off += (size_t)FH_ * K2_ * 2;
    __hip_bfloat16* WxT = (__hip_bfloat16*)(ws + off); off += (size_t)FH_ * D_ * 2;
    float* pre  = (float*)(ws + off); off += (size_t)N_ * FH_ * 4;
    __hip_bfloat16* hb = (__hip_bfloat16*)(ws + off); off += (size_t)N_ * K2_ * 2;
    float* cbuf = (float*)(ws + off); off += (size_t)N_ * H_ * 4;
    float* xproj = (float*)(ws + off);
    size_t per_t = (size_t)N_ * FH_ * 4;
    size_t rem = (ws_size > off) ? (ws_size - off) : 0;
    int Tc = (int)(rem / per_t);
    if (Tc > 16) Tc = 16;
    if (Tc < 1) Tc = 1;

    transpose_cast<<<dim3(FH_ / 32, H_ / 32), tb, 0, stream>>>(Wh, FH_, W2T, K2_, 0);
    transpose_cast<<<dim3(FH_ / 32, H_ / 32), tb, 0, stream>>>(Wattn, FH_, W2T, K2_, H_);
    transpose_cast<<<dim3(FH_ / 32, D_ / 32), tb, 0, stream>>>(Wx, FH_, WxT, D_, 0);
    init_hc<<<N_, 1024, 0, stream>>>(A, cbuf, hb);

    for (int t0 = 0; t0 < T_; t0 += Tc) {
        int tc = (T_ - t0 < Tc) ? (T_ - t0) : Tc;
        dim3 gx(FH_ / BN, tc * N_ / BM);
        gemm_bt<1><<<gx, 256, 0, stream>>>(x, nullptr, WxT, xproj, D_, t0);
        for (int tl = 0; tl < tc; tl++) {
            int t = t0 + tl;
            dim3 gs(FH_ / BN, N_ / BM);
            gemm_bt<0><<<gs, 256, 0, stream>>>(nullptr, hb, W2T, pre, K2_, 0);
            gates_attn<<<N_, 1024, 0, stream>>>(pre, xproj + (size_t)tl * N_ * FH_,
                                                b, A, cbuf, hb, out, t);
        }
    }
}